// Round 19
// baseline (444.097 us; speedup 1.0000x reference)
//
#include <hip/hip_runtime.h>
#include <math.h>

constexpr float DELTA_ = 2.5f;
#define NPB 32   // nodes per k_agg block
#define NBF 64   // stage-1 BN reduce blocks

typedef __attribute__((ext_vector_type(8))) short bf16x8;
typedef __attribute__((ext_vector_type(8))) _Float16 f16x8;
typedef __attribute__((ext_vector_type(4))) float f32x4;

__device__ inline ushort bf16h(float x){
  union { float f; unsigned u; } v; v.f = x;
  unsigned r = v.u + 0x7fffu + ((v.u >> 16) & 1u);
  return (ushort)(r >> 16);
}
__device__ inline float bf16f(ushort h){
  union { unsigned u; float f; } v; v.u = ((unsigned)h) << 16;
  return v.f;
}

// X2 layout v2 (slab-major): X2[((t*10+kt)*N + n)*64 + slot]
// slot = (j>>3)*16 + (hi?0:8) + (j&7), j = K-index within kt (0..31).

// ---------- U-weights: Wpk2[t][192][320] bf16 ----------
__global__ __launch_bounds__(256) void k_tU(const float* __restrict__ Uw, ushort* __restrict__ Wpk2){
  int i = blockIdx.x*256 + threadIdx.x;
  if (i >= 4*192*320) return;
  int k   = i % 320;
  int col = (i/320) % 192;
  int t   = i/(320*192);
  int path = col >> 6, o = col & 63;
  float v = 0.f;
  int src = -1;
  if (k < 64){ if (path == 0) src = k; }
  else        src = k + path*256;
  if (src >= 0) v = Uw[((size_t)(t*64 + o))*832 + src];
  Wpk2[i] = bf16h(v);
}

// ---------- mix weights ----------
__global__ __launch_bounds__(256) void k_tMm(const float* __restrict__ mixw, ushort* __restrict__ Wm2){
  int i = blockIdx.x*256 + threadIdx.x;
  if (i >= 256*256) return;
  Wm2[i] = bf16h(mixw[i]);
}

// ---------- M-weights (W_src | W_ef) in B-fragment layout, K=96 ----------
__global__ __launch_bounds__(256) void k_tW(const float* __restrict__ Mw, _Float16* __restrict__ Wall){
  int i = blockIdx.x*256 + threadIdx.x;
  if (i >= 4*4*3*64*8) return;
  int j     = i & 7;
  int lane  = (i >> 3) & 63;
  int slice = (i / 512) % 3;
  int cb    = (i / 1536) % 4;
  int t     = i / 6144;
  int ch = t*64 + cb*16 + (lane & 15);
  int k  = slice*32 + ((lane >> 4) & 3)*8 + j;
  int off = (k < 64) ? k : (128 + (k - 64));
  Wall[i] = (_Float16)Mw[(size_t)ch*160 + off];
}

__global__ __launch_bounds__(256) void k_hist(const int* __restrict__ dstv, int* __restrict__ cnt, int E){
  int e = blockIdx.x*256 + threadIdx.x;
  if (e < E) atomicAdd(&cnt[dstv[e]], 1);
}

__global__ __launch_bounds__(256) void k_scan1(const int* __restrict__ cnt, int* __restrict__ offs,
                                               int* __restrict__ bsum, int N){
  __shared__ int lds[256];
  int i = threadIdx.x;
  int g = blockIdx.x*256 + i;
  int v = (g < N) ? cnt[g] : 0;
  int acc = v;
  lds[i] = acc; __syncthreads();
  for (int s = 1; s < 256; s <<= 1){
    int t = (i >= s) ? lds[i - s] : 0;
    __syncthreads();
    acc += t; lds[i] = acc;
    __syncthreads();
  }
  if (g < N) offs[g] = acc - v;
  if (i == 255) bsum[blockIdx.x] = acc;
}

__global__ __launch_bounds__(256) void k_scan2(int* __restrict__ bsum, int NB){
  __shared__ int lds[256];
  int i = threadIdx.x;
  int v = (i < NB) ? bsum[i] : 0;
  int acc = v;
  lds[i] = acc; __syncthreads();
  for (int s = 1; s < 256; s <<= 1){
    int t = (i >= s) ? lds[i - s] : 0;
    __syncthreads();
    acc += t; lds[i] = acc;
    __syncthreads();
  }
  if (i < NB) bsum[i] = acc - v;
}

__global__ __launch_bounds__(256) void k_scan3(int* __restrict__ offs, const int* __restrict__ bsum, int N, int E){
  int g = blockIdx.x*256 + threadIdx.x;
  if (g < N) offs[g] += bsum[blockIdx.x];
  if (g == 0) offs[N] = E;
}

// ---------- CSR fill fused with permute ----------
__global__ __launch_bounds__(256) void k_fillp(const int* __restrict__ dstv, const int* __restrict__ srcv,
                                               const float* __restrict__ efeat, const int* __restrict__ offs,
                                               int* __restrict__ cur, int* __restrict__ esrc,
                                               _Float16* __restrict__ efh, int E){
  int e = blockIdx.x*256 + threadIdx.x;
  if (e >= E) return;
  int d = dstv[e];
  int pos = offs[d] + atomicAdd(&cur[d], 1);
  esrc[pos] = srcv[e];
  const float* src = efeat + (size_t)e*32;
  _Float16* dst = efh + (size_t)pos*32;
#pragma unroll
  for (int q = 0; q < 2; ++q){
    float4 v0 = *(const float4*)(src + q*16);
    float4 v1 = *(const float4*)(src + q*16 + 4);
    float4 v2 = *(const float4*)(src + q*16 + 8);
    float4 v3 = *(const float4*)(src + q*16 + 12);
    union { ushort4 u[4]; _Float16 h[16]; } cv;
    cv.h[0]=(_Float16)v0.x; cv.h[1]=(_Float16)v0.y; cv.h[2]=(_Float16)v0.z; cv.h[3]=(_Float16)v0.w;
    cv.h[4]=(_Float16)v1.x; cv.h[5]=(_Float16)v1.y; cv.h[6]=(_Float16)v1.z; cv.h[7]=(_Float16)v1.w;
    cv.h[8]=(_Float16)v2.x; cv.h[9]=(_Float16)v2.y; cv.h[10]=(_Float16)v2.z; cv.h[11]=(_Float16)v2.w;
    cv.h[12]=(_Float16)v3.x; cv.h[13]=(_Float16)v3.y; cv.h[14]=(_Float16)v3.z; cv.h[15]=(_Float16)v3.w;
    *(ushort4*)(dst + q*16)      = cv.u[0];
    *(ushort4*)(dst + q*16 + 4)  = cv.u[1];
    *(ushort4*)(dst + q*16 + 8)  = cv.u[2];
    *(ushort4*)(dst + q*16 + 12) = cv.u[3];
  }
}

// ---------- nfh = f16(nf), B = W_dst*h + M_b, X2 h-part (v2 layout) ----------
__global__ __launch_bounds__(256) void k_ab(const float* __restrict__ nf, const float* __restrict__ Mw,
                                            const float* __restrict__ Mb,
                                            _Float16* __restrict__ nfh, float* __restrict__ B,
                                            ushort* __restrict__ X2, int N){
  int c = threadIdx.x;
  int t = __builtin_amdgcn_readfirstlane(threadIdx.x >> 6);
  int d = c & 63;
  int kt = d >> 5, jlo = d & 31;
  int slot = (jlo >> 3)*16 + (jlo & 7);
  size_t slab = (size_t)(t*10 + kt)*N;
  float wd[64];
  const float* row = Mw + (size_t)c*160 + 64;
#pragma unroll
  for (int k = 0; k < 64; k += 4){
    float4 b = *(const float4*)(row + k);
    wd[k]=b.x; wd[k+1]=b.y; wd[k+2]=b.z; wd[k+3]=b.w;
  }
  float bias = Mb[c];
  for (int n = blockIdx.x; n < N; n += gridDim.x){
    const float* h = nf + (size_t)n*256 + t*64;
    float sb = 0.f;
#pragma unroll
    for (int k = 0; k < 64; k += 4){
      float4 h4 = *(const float4*)(h + k);
      sb = fmaf(wd[k], h4.x, sb);
      sb = fmaf(wd[k+1], h4.y, sb);
      sb = fmaf(wd[k+2], h4.z, sb);
      sb = fmaf(wd[k+3], h4.w, sb);
    }
    B[(size_t)n*256 + c] = sb + bias;
    float v = nf[(size_t)n*256 + c];
    nfh[(size_t)n*256 + c] = (_Float16)v;
    ushort hi = bf16h(v);
    size_t base = (slab + n)*64 + slot;
    X2[base]     = hi;
    X2[base + 8] = bf16h(v - bf16f(hi));
  }
}

// ---------- aggregation v5: r18 + register prefetch across a counted-drain barrier ----------
// Window w's fragments are preloaded into regs during window w-1's MFMA phase;
// barrier-2 drains only lgkm (eps ds_writes) via raw s_barrier so the prefetch
// global loads stay in flight across it, covered by phase B's VALU walk.
__global__ __launch_bounds__(256) void k_agg(const int* __restrict__ offs, const int* __restrict__ esrc,
                                             const _Float16* __restrict__ efh,
                                             const _Float16* __restrict__ nfh, const float* __restrict__ B,
                                             const _Float16* __restrict__ Wall,
                                             ushort* __restrict__ X2, float* __restrict__ sc, int N, int E){
  __shared__ _Float16 eps[256][68];
  int tid = threadIdx.x;
  int lane = tid & 63, wv = tid >> 6;
  int li = lane & 15, kq = lane >> 4;
  int c = tid;
  int tw = c >> 6, d = c & 63;
  int jlo = d & 31;
  int slot = (jlo >> 3)*16 + (jlo & 7);
  int ktd = d >> 5;

  int n0 = blockIdx.x * NPB;
  if (n0 >= N) return;
  int n1 = n0 + NPB; if (n1 > N) n1 = N;
  int oS = offs[n0], oE = offs[n1];

  f16x8 bf[4][3];
#pragma unroll
  for (int cb = 0; cb < 4; ++cb)
#pragma unroll
    for (int sl = 0; sl < 3; ++sl)
      bf[cb][sl] = *(const f16x8*)(Wall + ((((size_t)wv*4 + cb)*3 + sl)*64 + lane)*8);

  int cur = n0;
  int curstart = oS;
  int nextoff = offs[n0 + 1];
  float s = 0.f, ss = 0.f;
  float mx = -__builtin_huge_valf(), mn = __builtin_huge_valf();

#define PUTX2(S, VAL)                                                             \
  { size_t base = ((size_t)(tw*10 + 2 + (S)*2 + ktd)*N + cur)*64 + slot;          \
    ushort h2 = bf16h(VAL);                                                       \
    X2[base] = h2; X2[base + 8] = bf16h((VAL) - bf16f(h2)); }

#define FINALIZE(CNT)                                                             \
  {                                                                                \
    float b = B[(size_t)cur*256 + c];                                              \
    float deg = (float)(CNT);                                                      \
    float degc = fmaxf(deg, 1.f);                                                  \
    float inv = 1.f / degc;                                                        \
    float S_  = fmaf(deg, b, s);                                                   \
    float SS_ = fmaf(deg, b*b, fmaf(2.f*b, s, ss));                                \
    float mean = S_ * inv;                                                         \
    float var  = fmaxf(SS_ * inv - mean*mean, 0.f);                                \
    float sd   = sqrtf(var + 1e-30f);                                              \
    float MX = ((CNT) > 0) ? (b + mx) : 0.f;                                       \
    float MN = ((CNT) > 0) ? (b + mn) : 0.f;                                       \
    PUTX2(0, mean) PUTX2(1, MX) PUTX2(2, MN) PUTX2(3, sd)                          \
    if (tid == 0){                                                                 \
      float logd = logf(deg + 1.f);                                                \
      sc[(size_t)cur*2]     = logd * (1.f / DELTA_);                               \
      sc[(size_t)cur*2 + 1] = ((CNT) > 0) ? (DELTA_ / fmaxf(logd, 1e-12f)) : 0.f;  \
    }                                                                              \
  }

  f16x8 pa0[4], pa1[4], pa2[4];
#define PRELOAD(W0)                                                               \
  { _Pragma("unroll")                                                             \
    for (int ch4 = 0; ch4 < 4; ++ch4){                                            \
      int pos = (W0) + ch4*16 + li; if (pos > E - 1) pos = E - 1;                 \
      int src = esrc[pos];                                                        \
      const _Float16* hp = nfh + (size_t)src*256 + wv*64;                         \
      pa0[ch4] = *(const f16x8*)(hp + kq*8);                                      \
      pa1[ch4] = *(const f16x8*)(hp + 32 + kq*8);                                 \
      pa2[ch4] = *(const f16x8*)(efh + (size_t)pos*32 + kq*8);                    \
    } }

  if (oS < oE) PRELOAD(oS)

  for (int w0 = oS; w0 < oE; w0 += 64){
    __syncthreads();   // full drain: prev phase-B eps reads done; prefetch data needed now anyway
#pragma unroll
    for (int ch4 = 0; ch4 < 4; ++ch4){
#pragma unroll
      for (int cb = 0; cb < 4; ++cb){
        f32x4 acc = __builtin_amdgcn_mfma_f32_16x16x32_f16(pa0[ch4], bf[cb][0], (f32x4)0.f, 0, 0, 0);
        acc = __builtin_amdgcn_mfma_f32_16x16x32_f16(pa1[ch4], bf[cb][1], acc, 0, 0, 0);
        acc = __builtin_amdgcn_mfma_f32_16x16x32_f16(pa2[ch4], bf[cb][2], acc, 0, 0, 0);
        union { ushort4 u4; _Float16 h[4]; } st;
        st.h[0] = (_Float16)acc[0];
        st.h[1] = (_Float16)acc[1];
        st.h[2] = (_Float16)acc[2];
        st.h[3] = (_Float16)acc[3];
        *(ushort4*)(&eps[wv*64 + cb*16 + li][ch4*16 + kq*4]) = st.u4;
      }
    }
    // prefetch next window while this window's phase B runs (loads cross the raw barrier)
    int wn = w0 + 64;
    if (wn < oE) PRELOAD(wn)
    // eps visibility needs only lgkm drain; keep prefetch vmcnt in flight
    asm volatile("s_waitcnt lgkmcnt(0)" ::: "memory");
    __builtin_amdgcn_s_barrier();
    __builtin_amdgcn_sched_barrier(0);

    int wend = w0 + 64; if (wend > oE) wend = oE;
    for (int g = 0; g < 64; g += 4){
      if (w0 + g >= wend) break;
      union { ushort4 u4; _Float16 h[4]; } ld;
      ld.u4 = *(const ushort4*)(&eps[c][g]);
#pragma unroll
      for (int r = 0; r < 4; ++r){
        int idx = w0 + g + r;
        if (idx >= wend) break;
        while (idx == nextoff){
          FINALIZE(nextoff - curstart)
          curstart = nextoff;
          ++cur;
          nextoff = offs[cur + 1];
          s = 0.f; ss = 0.f;
          mx = -__builtin_huge_valf(); mn = __builtin_huge_valf();
        }
        float m = (float)ld.h[r];
        s += m;
        ss = fmaf(m, m, ss);
        mx = fmaxf(mx, m);
        mn = fminf(mn, m);
      }
    }
  }

  while (cur < n1){
    FINALIZE(nextoff - curstart)
    curstart = nextoff;
    ++cur;
    if (cur < n1) nextoff = offs[cur + 1];
    s = 0.f; ss = 0.f;
    mx = -__builtin_huge_valf(); mn = __builtin_huge_valf();
  }
#undef FINALIZE
#undef PUTX2
#undef PRELOAD
}

// ---------- U GEMM: LDS-free MFMA, slab-major A-loads + fused BN partials ----------
__global__ __launch_bounds__(256) void k_u(const ushort* __restrict__ X2, const ushort* __restrict__ Wpk2,
                                           const float* __restrict__ sc, const float* __restrict__ Ub,
                                           float* __restrict__ uout, float* __restrict__ part,
                                           int Nn, int NBLK){
  __shared__ float su[64][68];
  __shared__ float pbn[2][4][64];
  int tid = threadIdx.x;
  int t   = blockIdx.y;
  int nbase = blockIdx.x*64;
  int lane = tid & 63, wv = tid >> 6;
  int li = lane & 15, kc = lane >> 4;
  int cbase = wv*48;

  f32x4 acc[4][3];
#pragma unroll
  for (int ri = 0; ri < 4; ++ri)
#pragma unroll
    for (int ci = 0; ci < 3; ++ci) acc[ri][ci] = (f32x4)0.f;

  const ushort* wb = Wpk2 + (size_t)t*192*320;

#pragma unroll 2
  for (int kt = 0; kt < 10; ++kt){
    const ushort* slab = X2 + (size_t)(t*10 + kt)*Nn*64;
    bf16x8 ah[4], al[4], bh[3];
#pragma unroll
    for (int ri = 0; ri < 4; ++ri){
      int row = nbase + ri*16 + li;
      if (row >= Nn) row = Nn - 1;
      const ushort* ap = slab + (size_t)row*64 + kc*16;
      ah[ri] = *(const bf16x8*)(ap);
      al[ri] = *(const bf16x8*)(ap + 8);
    }
#pragma unroll
    for (int ci = 0; ci < 3; ++ci){
      int col = cbase + ci*16 + li;
      bh[ci] = *(const bf16x8*)(wb + (size_t)col*320 + kt*32 + kc*8);
    }
#pragma unroll
    for (int ci = 0; ci < 3; ++ci)
#pragma unroll
      for (int ri = 0; ri < 4; ++ri){
        acc[ri][ci] = __builtin_amdgcn_mfma_f32_16x16x32_bf16(ah[ri], bh[ci], acc[ri][ci], 0, 0, 0);
        acc[ri][ci] = __builtin_amdgcn_mfma_f32_16x16x32_bf16(al[ri], bh[ci], acc[ri][ci], 0, 0, 0);
      }
  }

#define Y1_STORE(CI, OB) { _Pragma("unroll") for (int ri = 0; ri < 4; ++ri)               \
    { _Pragma("unroll") for (int r = 0; r < 4; ++r)                                        \
      su[ri*16 + kc*4 + r][(OB) + li] = acc[ri][CI][r]; } }
#define Y_ADD(CI, OB, SCOFF) { _Pragma("unroll") for (int ri = 0; ri < 4; ++ri)           \
    { _Pragma("unroll") for (int r = 0; r < 4; ++r){                                       \
      int node = ri*16 + kc*4 + r;                                                        \
      int gn = nbase + node; int gnc = (gn < Nn) ? gn : (Nn - 1);                          \
      float scl = sc[(size_t)gnc*2 + (SCOFF)];                                            \
      su[node][(OB) + li] += scl * acc[ri][CI][r]; } } }

  if (wv == 0){ Y1_STORE(0, 0)  Y1_STORE(1, 16) Y1_STORE(2, 32) }
  else if (wv == 1){ Y1_STORE(0, 48) }
  __syncthreads();
  if (wv == 1){ Y_ADD(1, 0, 0)  Y_ADD(2, 16, 0) }
  else if (wv == 2){ Y_ADD(0, 32, 0) Y_ADD(1, 48, 0) }
  __syncthreads();
  if (wv == 2){ Y_ADD(2, 0, 1) }
  else if (wv == 3){ Y_ADD(0, 16, 1) Y_ADD(1, 32, 1) Y_ADD(2, 48, 1) }
  __syncthreads();
#undef Y1_STORE
#undef Y_ADD

  for (int idx = tid; idx < 64*16; idx += 256){
    int n = idx >> 4, o4 = (idx & 15)*4;
    int gn = nbase + n;
    if (gn < Nn){
      float4 v = *(float4*)(&su[n][o4]);
      const float* ubp = Ub + t*64 + o4;
      v.x += ubp[0]; v.y += ubp[1]; v.z += ubp[2]; v.w += ubp[3];
      *(float4*)(&uout[(size_t)gn*256 + t*64 + o4]) = v;
    }
  }

  {
    int cl = tid & 63, grp = tid >> 6;
    float ubv = Ub[t*64 + cl];
    float ps = 0.f, pss = 0.f;
#pragma unroll
    for (int q = 0; q < 16; ++q){
      int nn = grp*16 + q;
      if (nbase + nn < Nn){
        float v = su[nn][cl] + ubv;
        ps += v;
        pss = fmaf(v, v, pss);
      }
    }
    pbn[0][grp][cl] = ps;
    pbn[1][grp][cl] = pss;
  }
  __syncthreads();
  if (tid < 128){
    int which = tid >> 6, cl = tid & 63;
    float v = pbn[which][0][cl] + pbn[which][1][cl] + pbn[which][2][cl] + pbn[which][3][cl];
    part[((size_t)t*NBLK + blockIdx.x)*128 + which*64 + cl] = v;
  }
}

// ---------- BN reduce stage 1 ----------
__global__ __launch_bounds__(256) void k_bnred(const float* __restrict__ part, float* __restrict__ part2,
                                               int NBLK){
  int g = blockIdx.x;
  int tid = threadIdx.x;
  int chunk = (NBLK + NBF - 1) / NBF;
  int b0 = g * chunk;
  int b1 = b0 + chunk; if (b1 > NBLK) b1 = NBLK;
#pragma unroll
  for (int half = 0; half < 2; ++half){
    int o = half*256 + tid;
    int t = o >> 7, idx = o & 127;
    float s = 0.f;
    for (int b = b0; b < b1; ++b)
      s += part[((size_t)t*NBLK + b)*128 + idx];
    part2[(size_t)g*512 + o] = s;
  }
}

// ---------- BN finalize ----------
__global__ __launch_bounds__(256) void k_bnfin(const float* __restrict__ part2, const float* __restrict__ gam,
                                               const float* __restrict__ bet, float* __restrict__ bnsc, int N){
  int c = threadIdx.x;
  int t = c >> 6, cl = c & 63;
  float s0 = 0.f, s1 = 0.f, t0 = 0.f, t1 = 0.f;
#pragma unroll 4
  for (int b = 0; b < NBF; b += 2){
    s0 += part2[(size_t)b*512 + t*128 + cl];
    t0 += part2[(size_t)b*512 + t*128 + 64 + cl];
    s1 += part2[(size_t)(b+1)*512 + t*128 + cl];
    t1 += part2[(size_t)(b+1)*512 + t*128 + 64 + cl];
  }
  float s = s0 + s1, ss = t0 + t1;
  float invN = 1.f / (float)N;
  float mu  = s * invN;
  float ex2 = ss * invN;
  float var = fmaxf(ex2 - mu*mu, 0.f);
  float inv = 1.f / sqrtf(var + 1e-5f);
  float scale = gam[c] * inv;
  bnsc[c]       = scale;
  bnsc[256 + c] = bet[c] - mu*scale;
}

// ---------- mix GEMM: reads u directly (BN folded in-reg), fused epilogue ----------
__global__ __launch_bounds__(256) void k_mix(const float* __restrict__ u, const ushort* __restrict__ Wm2,
                                             const float* __restrict__ bnsc,
                                             const float* __restrict__ mixb, const float* __restrict__ nf,
                                             float* __restrict__ outp, int Nn){
  int tid = threadIdx.x;
  int nbase = blockIdx.x*64;
  int lane = tid & 63, wv = tid >> 6;
  int li = lane & 15, kc = lane >> 4;

  f32x4 acc[4][4];
#pragma unroll
  for (int ri = 0; ri < 4; ++ri)
#pragma unroll
    for (int ci = 0; ci < 4; ++ci) acc[ri][ci] = (f32x4)0.f;

#pragma unroll 2
  for (int kt = 0; kt < 8; ++kt){
    int k0 = kt*32 + kc*8;
    float4 s40 = *(const float4*)(bnsc + k0);
    float4 s41 = *(const float4*)(bnsc + k0 + 4);
    float4 h40 = *(const float4*)(bnsc + 256 + k0);
    float4 h41 = *(const float4*)(bnsc + 256 + k0 + 4);
    bf16x8 ah[4], al[4], bh[4];
#pragma unroll
    for (int ri = 0; ri < 4; ++ri){
      int row = nbase + ri*16 + li;
      if (row >= Nn) row = Nn - 1;
      const float* up = u + (size_t)row*256 + k0;
      float4 v0 = *(const float4*)(up);
      float4 v1 = *(const float4*)(up + 4);
      float x[8];
      x[0] = fmaf(v0.x, s40.x, h40.x); x[1] = fmaf(v0.y, s40.y, h40.y);
      x[2] = fmaf(v0.z, s40.z, h40.z); x[3] = fmaf(v0.w, s40.w, h40.w);
      x[4] = fmaf(v1.x, s41.x, h41.x); x[5] = fmaf(v1.y, s41.y, h41.y);
      x[6] = fmaf(v1.z, s41.z, h41.z); x[7] = fmaf(v1.w, s41.w, h41.w);
      union { bf16x8 v; ushort u[8]; } hh, ll;
#pragma unroll
      for (int q = 0; q < 8; ++q){
        ushort hb = bf16h(x[q]);
        hh.u[q] = hb;
        ll.u[q] = bf16h(x[q] - bf16f(hb));
      }
      ah[ri] = hh.v;
      al[ri] = ll.v;
    }
#pragma unroll
    for (int ci = 0; ci < 4; ++ci){
      int col = wv*64 + ci*16 + li;
      bh[ci] = *(const bf16x8*)(Wm2 + (size_t)col*256 + kt*32 + kc*8);
    }
#pragma unroll
    for (int ci = 0; ci < 4; ++ci)
#pragma unroll
      for (int ri = 0; ri < 4; ++ri){
        acc[ri][ci] = __builtin_amdgcn_mfma_f32_16x16x32_bf16(ah[ri], bh[ci], acc[ri][ci], 0, 0, 0);
        acc[ri][ci] = __builtin_amdgcn_mfma_f32_16x16x32_bf16(al[ri], bh[ci], acc[ri][ci], 0, 0, 0);
      }
  }

  __syncthreads();
#pragma unroll
  for (int ri = 0; ri < 4; ++ri){
#pragma unroll
    for (int r = 0; r < 4; ++r){
      int node = ri*16 + kc*4 + r;
      int gn = nbase + node;
      if (gn < Nn){
#pragma unroll
        for (int ci = 0; ci < 4; ++ci){
          int col = wv*64 + ci*16 + li;
          float m = acc[ri][ci][r] + mixb[col];
          m = (m > 0.f) ? m : 0.01f*m;
          float o = m + nf[(size_t)gn*256 + col];
          outp[(size_t)gn*256 + col] = fmaxf(o, 0.f);
        }
      }
    }
  }
}

// ---------- host launcher ----------
extern "C" void kernel_launch(void* const* d_in, const int* in_sizes, int n_in,
                              void* d_out, int out_size, void* d_ws, size_t ws_size,
                              hipStream_t stream){
  const float* nf   = (const float*)d_in[0];
  const float* ef   = (const float*)d_in[1];
  const int*   srcv = (const int*)  d_in[2];
  const int*   dstv = (const int*)  d_in[3];
  const float* Mw   = (const float*)d_in[4];
  const float* Mb   = (const float*)d_in[5];
  const float* Uw   = (const float*)d_in[6];
  const float* Ub   = (const float*)d_in[7];
  const float* gam  = (const float*)d_in[8];
  const float* bet  = (const float*)d_in[9];
  const float* mixw = (const float*)d_in[10];
  const float* mixb = (const float*)d_in[11];
  int N = in_sizes[0] / 256;
  int E = in_sizes[2];
  float* out = (float*)d_out;
  int NBLK = (N + 63)/64;

  char* wp = (char*)d_ws;
  auto alloc = [&](size_t bytes){
    char* p = wp;
    wp += (bytes + 1023) & ~(size_t)1023;
    return (void*)p;
  };
  int*      cnt   = (int*)     alloc((size_t)N*4);
  int*      offs  = (int*)     alloc((size_t)(N+1)*4);
  int*      cur   = (int*)     alloc((size_t)N*4);
  int*      bsum  = (int*)     alloc(256*4);
  int*      esrc  = (int*)     alloc((size_t)E*4);
  _Float16* efh   = (_Float16*)alloc((size_t)E*32*2);
  _Float16* nfh   = (_Float16*)alloc((size_t)N*256*2);
  float*    B     = (float*)   alloc((size_t)N*256*4);
  float*    sc    = (float*)   alloc((size_t)N*2*4);
  float*    part  = (float*)   alloc((size_t)4*NBLK*128*4);
  float*    part2 = (float*)   alloc((size_t)NBF*512*4);
  float*    bnsc  = (float*)   alloc(512*4);
  ushort*   X2    = (ushort*)  alloc((size_t)N*2560*2);
  ushort*   Wpk2  = (ushort*)  alloc((size_t)4*192*320*2);
  ushort*   Wm2   = (ushort*)  alloc((size_t)256*256*2);
  _Float16* Wall  = (_Float16*)alloc((size_t)4*4*3*64*8*2);

  hipMemsetAsync(cnt,  0, (size_t)N*4,  stream);
  hipMemsetAsync(cur,  0, (size_t)N*4,  stream);

  k_tU  <<<(4*192*320 + 255)/256, 256, 0, stream>>>(Uw, Wpk2);
  k_tMm <<<(256*256 + 255)/256, 256, 0, stream>>>(mixw, Wm2);
  k_tW  <<<(4*4*3*64*8 + 255)/256, 256, 0, stream>>>(Mw, Wall);
  k_hist<<<(E + 255)/256, 256, 0, stream>>>(dstv, cnt, E);
  k_ab  <<<2048, 256, 0, stream>>>(nf, Mw, Mb, nfh, B, X2, N);

  int NB = (N + 255)/256;
  k_scan1<<<NB, 256, 0, stream>>>(cnt, offs, bsum, N);
  k_scan2<<<1, 256, 0, stream>>>(bsum, NB);
  k_scan3<<<NB, 256, 0, stream>>>(offs, bsum, N, E);
  k_fillp<<<(E + 255)/256, 256, 0, stream>>>(dstv, srcv, ef, offs, cur, esrc, efh, E);

  k_agg<<<(N + NPB - 1)/NPB, 256, 0, stream>>>(offs, esrc, efh, nfh, B, Wall, X2, sc, N, E);

  dim3 ugrid(NBLK, 4);
  k_u<<<ugrid, 256, 0, stream>>>(X2, Wpk2, sc, Ub, out, part, N, NBLK);

  k_bnred<<<NBF, 256, 0, stream>>>(part, part2, NBLK);
  k_bnfin<<<1, 256, 0, stream>>>(part2, gam, bet, bnsc, N);
  k_mix  <<<NBLK, 256, 0, stream>>>(out, Wm2, bnsc, mixb, nf, out, N);
}

// Round 20
// 419.180 us; speedup vs baseline: 1.0594x; 1.0594x over previous
//
#include <hip/hip_runtime.h>
#include <math.h>

constexpr float DELTA_ = 2.5f;
#define NPB 32   // nodes per k_agg block
#define NBF 64   // stage-1 BN reduce blocks

typedef __attribute__((ext_vector_type(8))) short bf16x8;
typedef __attribute__((ext_vector_type(8))) _Float16 f16x8;
typedef __attribute__((ext_vector_type(4))) float f32x4;

__device__ inline ushort bf16h(float x){
  union { float f; unsigned u; } v; v.f = x;
  unsigned r = v.u + 0x7fffu + ((v.u >> 16) & 1u);
  return (ushort)(r >> 16);
}
__device__ inline float bf16f(ushort h){
  union { unsigned u; float f; } v; v.u = ((unsigned)h) << 16;
  return v.f;
}

// X2 layout v2 (slab-major): X2[((t*10+kt)*N + n)*64 + slot]
// slot = (j>>3)*16 + (hi?0:8) + (j&7), j = K-index within kt (0..31).
// k_u fragment: ah at +kc*16, al at +kc*16+8; row stride = 128 B (coalesced).

// ---------- U-weights: Wpk2[t][192][320] bf16 (col = path*64+o; path1/2 zero h-rows) ----------
__global__ __launch_bounds__(256) void k_tU(const float* __restrict__ Uw, ushort* __restrict__ Wpk2){
  int i = blockIdx.x*256 + threadIdx.x;          // i = (t*192+col)*320 + k
  if (i >= 4*192*320) return;
  int k   = i % 320;
  int col = (i/320) % 192;
  int t   = i/(320*192);
  int path = col >> 6, o = col & 63;
  float v = 0.f;
  int src = -1;
  if (k < 64){ if (path == 0) src = k; }
  else        src = k + path*256;
  if (src >= 0) v = Uw[((size_t)(t*64 + o))*832 + src];
  Wpk2[i] = bf16h(v);
}

// ---------- mix weights: Wm2[col][256] bf16 ----------
__global__ __launch_bounds__(256) void k_tMm(const float* __restrict__ mixw, ushort* __restrict__ Wm2){
  int i = blockIdx.x*256 + threadIdx.x;
  if (i >= 256*256) return;
  Wm2[i] = bf16h(mixw[i]);
}

// ---------- M-weights (W_src | W_ef) in B-fragment layout, K=96 ----------
__global__ __launch_bounds__(256) void k_tW(const float* __restrict__ Mw, _Float16* __restrict__ Wall){
  int i = blockIdx.x*256 + threadIdx.x;
  if (i >= 4*4*3*64*8) return;
  int j     = i & 7;
  int lane  = (i >> 3) & 63;
  int slice = (i / 512) % 3;
  int cb    = (i / 1536) % 4;
  int t     = i / 6144;
  int ch = t*64 + cb*16 + (lane & 15);
  int k  = slice*32 + ((lane >> 4) & 3)*8 + j;
  int off = (k < 64) ? k : (128 + (k - 64));
  Wall[i] = (_Float16)Mw[(size_t)ch*160 + off];
}

__global__ __launch_bounds__(256) void k_hist(const int* __restrict__ dstv, int* __restrict__ cnt, int E){
  int e = blockIdx.x*256 + threadIdx.x;
  if (e < E) atomicAdd(&cnt[dstv[e]], 1);
}

__global__ __launch_bounds__(256) void k_scan1(const int* __restrict__ cnt, int* __restrict__ offs,
                                               int* __restrict__ bsum, int N){
  __shared__ int lds[256];
  int i = threadIdx.x;
  int g = blockIdx.x*256 + i;
  int v = (g < N) ? cnt[g] : 0;
  int acc = v;
  lds[i] = acc; __syncthreads();
  for (int s = 1; s < 256; s <<= 1){
    int t = (i >= s) ? lds[i - s] : 0;
    __syncthreads();
    acc += t; lds[i] = acc;
    __syncthreads();
  }
  if (g < N) offs[g] = acc - v;
  if (i == 255) bsum[blockIdx.x] = acc;
}

__global__ __launch_bounds__(256) void k_scan2(int* __restrict__ bsum, int NB){
  __shared__ int lds[256];
  int i = threadIdx.x;
  int v = (i < NB) ? bsum[i] : 0;
  int acc = v;
  lds[i] = acc; __syncthreads();
  for (int s = 1; s < 256; s <<= 1){
    int t = (i >= s) ? lds[i - s] : 0;
    __syncthreads();
    acc += t; lds[i] = acc;
    __syncthreads();
  }
  if (i < NB) bsum[i] = acc - v;
}

__global__ __launch_bounds__(256) void k_scan3(int* __restrict__ offs, const int* __restrict__ bsum, int N, int E){
  int g = blockIdx.x*256 + threadIdx.x;
  if (g < N) offs[g] += bsum[blockIdx.x];
  if (g == 0) offs[N] = E;
}

// ---------- CSR fill fused with permute ----------
__global__ __launch_bounds__(256) void k_fillp(const int* __restrict__ dstv, const int* __restrict__ srcv,
                                               const float* __restrict__ efeat, const int* __restrict__ offs,
                                               int* __restrict__ cur, int* __restrict__ esrc,
                                               _Float16* __restrict__ efh, int E){
  int e = blockIdx.x*256 + threadIdx.x;
  if (e >= E) return;
  int d = dstv[e];
  int pos = offs[d] + atomicAdd(&cur[d], 1);
  esrc[pos] = srcv[e];
  const float* src = efeat + (size_t)e*32;
  _Float16* dst = efh + (size_t)pos*32;
#pragma unroll
  for (int q = 0; q < 2; ++q){
    float4 v0 = *(const float4*)(src + q*16);
    float4 v1 = *(const float4*)(src + q*16 + 4);
    float4 v2 = *(const float4*)(src + q*16 + 8);
    float4 v3 = *(const float4*)(src + q*16 + 12);
    union { ushort4 u[4]; _Float16 h[16]; } cv;
    cv.h[0]=(_Float16)v0.x; cv.h[1]=(_Float16)v0.y; cv.h[2]=(_Float16)v0.z; cv.h[3]=(_Float16)v0.w;
    cv.h[4]=(_Float16)v1.x; cv.h[5]=(_Float16)v1.y; cv.h[6]=(_Float16)v1.z; cv.h[7]=(_Float16)v1.w;
    cv.h[8]=(_Float16)v2.x; cv.h[9]=(_Float16)v2.y; cv.h[10]=(_Float16)v2.z; cv.h[11]=(_Float16)v2.w;
    cv.h[12]=(_Float16)v3.x; cv.h[13]=(_Float16)v3.y; cv.h[14]=(_Float16)v3.z; cv.h[15]=(_Float16)v3.w;
    *(ushort4*)(dst + q*16)      = cv.u[0];
    *(ushort4*)(dst + q*16 + 4)  = cv.u[1];
    *(ushort4*)(dst + q*16 + 8)  = cv.u[2];
    *(ushort4*)(dst + q*16 + 12) = cv.u[3];
  }
}

// ---------- nfh = f16(nf), B = W_dst*h + M_b, X2 h-part (v2 layout) ----------
__global__ __launch_bounds__(256) void k_ab(const float* __restrict__ nf, const float* __restrict__ Mw,
                                            const float* __restrict__ Mb,
                                            _Float16* __restrict__ nfh, float* __restrict__ B,
                                            ushort* __restrict__ X2, int N){
  int c = threadIdx.x;
  int t = __builtin_amdgcn_readfirstlane(threadIdx.x >> 6);
  int d = c & 63;
  int kt = d >> 5, jlo = d & 31;
  int slot = (jlo >> 3)*16 + (jlo & 7);
  size_t slab = (size_t)(t*10 + kt)*N;
  float wd[64];
  const float* row = Mw + (size_t)c*160 + 64;
#pragma unroll
  for (int k = 0; k < 64; k += 4){
    float4 b = *(const float4*)(row + k);
    wd[k]=b.x; wd[k+1]=b.y; wd[k+2]=b.z; wd[k+3]=b.w;
  }
  float bias = Mb[c];
  for (int n = blockIdx.x; n < N; n += gridDim.x){
    const float* h = nf + (size_t)n*256 + t*64;
    float sb = 0.f;
#pragma unroll
    for (int k = 0; k < 64; k += 4){
      float4 h4 = *(const float4*)(h + k);
      sb = fmaf(wd[k], h4.x, sb);
      sb = fmaf(wd[k+1], h4.y, sb);
      sb = fmaf(wd[k+2], h4.z, sb);
      sb = fmaf(wd[k+3], h4.w, sb);
    }
    B[(size_t)n*256 + c] = sb + bias;
    float v = nf[(size_t)n*256 + c];
    nfh[(size_t)n*256 + c] = (_Float16)v;
    ushort hi = bf16h(v);
    size_t base = (slab + n)*64 + slot;
    X2[base]     = hi;
    X2[base + 8] = bf16h(v - bf16f(hi));
  }
}

// ---------- aggregation v4 (r13-r17 validated), FINALIZE writes v2 layout ----------
__global__ __launch_bounds__(256) void k_agg(const int* __restrict__ offs, const int* __restrict__ esrc,
                                             const _Float16* __restrict__ efh,
                                             const _Float16* __restrict__ nfh, const float* __restrict__ B,
                                             const _Float16* __restrict__ Wall,
                                             ushort* __restrict__ X2, float* __restrict__ sc, int N, int E){
  __shared__ _Float16 eps[256][68];
  int tid = threadIdx.x;
  int lane = tid & 63, wv = tid >> 6;
  int li = lane & 15, kq = lane >> 4;
  int c = tid;
  int tw = c >> 6, d = c & 63;
  int jlo = d & 31;
  int slot = (jlo >> 3)*16 + (jlo & 7);
  int ktd = d >> 5;                               // 0 or 1

  int n0 = blockIdx.x * NPB;
  if (n0 >= N) return;
  int n1 = n0 + NPB; if (n1 > N) n1 = N;
  int oS = offs[n0], oE = offs[n1];

  f16x8 bf[4][3];
#pragma unroll
  for (int cb = 0; cb < 4; ++cb)
#pragma unroll
    for (int sl = 0; sl < 3; ++sl)
      bf[cb][sl] = *(const f16x8*)(Wall + ((((size_t)wv*4 + cb)*3 + sl)*64 + lane)*8);

  int cur = n0;
  int curstart = oS;
  int nextoff = offs[n0 + 1];
  float s = 0.f, ss = 0.f;
  float mx = -__builtin_huge_valf(), mn = __builtin_huge_valf();

  // agg slot S (0..3) lives at kt = 2 + S*2 + ktd
#define PUTX2(S, VAL)                                                             \
  { size_t base = ((size_t)(tw*10 + 2 + (S)*2 + ktd)*N + cur)*64 + slot;          \
    ushort h2 = bf16h(VAL);                                                       \
    X2[base] = h2; X2[base + 8] = bf16h((VAL) - bf16f(h2)); }

#define FINALIZE(CNT)                                                             \
  {                                                                                \
    float b = B[(size_t)cur*256 + c];                                              \
    float deg = (float)(CNT);                                                      \
    float degc = fmaxf(deg, 1.f);                                                  \
    float inv = 1.f / degc;                                                        \
    float S_  = fmaf(deg, b, s);                                                   \
    float SS_ = fmaf(deg, b*b, fmaf(2.f*b, s, ss));                                \
    float mean = S_ * inv;                                                         \
    float var  = fmaxf(SS_ * inv - mean*mean, 0.f);                                \
    float sd   = sqrtf(var + 1e-30f);                                              \
    float MX = ((CNT) > 0) ? (b + mx) : 0.f;                                       \
    float MN = ((CNT) > 0) ? (b + mn) : 0.f;                                       \
    PUTX2(0, mean) PUTX2(1, MX) PUTX2(2, MN) PUTX2(3, sd)                          \
    if (tid == 0){                                                                 \
      float logd = logf(deg + 1.f);                                                \
      sc[(size_t)cur*2]     = logd * (1.f / DELTA_);                               \
      sc[(size_t)cur*2 + 1] = ((CNT) > 0) ? (DELTA_ / fmaxf(logd, 1e-12f)) : 0.f;  \
    }                                                                              \
  }

  for (int w0 = oS; w0 < oE; w0 += 64){
    __syncthreads();
#pragma unroll
    for (int ch4 = 0; ch4 < 4; ++ch4){
      int pos = w0 + ch4*16 + li; if (pos > E - 1) pos = E - 1;
      int src = esrc[pos];
      const _Float16* hp = nfh + (size_t)src*256 + wv*64;
      f16x8 a0 = *(const f16x8*)(hp + kq*8);
      f16x8 a1 = *(const f16x8*)(hp + 32 + kq*8);
      f16x8 a2 = *(const f16x8*)(efh + (size_t)pos*32 + kq*8);
#pragma unroll
      for (int cb = 0; cb < 4; ++cb){
        f32x4 acc = __builtin_amdgcn_mfma_f32_16x16x32_f16(a0, bf[cb][0], (f32x4)0.f, 0, 0, 0);
        acc = __builtin_amdgcn_mfma_f32_16x16x32_f16(a1, bf[cb][1], acc, 0, 0, 0);
        acc = __builtin_amdgcn_mfma_f32_16x16x32_f16(a2, bf[cb][2], acc, 0, 0, 0);
        union { ushort4 u4; _Float16 h[4]; } st;
        st.h[0] = (_Float16)acc[0];
        st.h[1] = (_Float16)acc[1];
        st.h[2] = (_Float16)acc[2];
        st.h[3] = (_Float16)acc[3];
        *(ushort4*)(&eps[wv*64 + cb*16 + li][ch4*16 + kq*4]) = st.u4;
      }
    }
    __syncthreads();

    int wend = w0 + 64; if (wend > oE) wend = oE;
    for (int g = 0; g < 64; g += 4){
      if (w0 + g >= wend) break;
      union { ushort4 u4; _Float16 h[4]; } ld;
      ld.u4 = *(const ushort4*)(&eps[c][g]);
#pragma unroll
      for (int r = 0; r < 4; ++r){
        int idx = w0 + g + r;
        if (idx >= wend) break;
        while (idx == nextoff){
          FINALIZE(nextoff - curstart)
          curstart = nextoff;
          ++cur;
          nextoff = offs[cur + 1];
          s = 0.f; ss = 0.f;
          mx = -__builtin_huge_valf(); mn = __builtin_huge_valf();
        }
        float m = (float)ld.h[r];
        s += m;
        ss = fmaf(m, m, ss);
        mx = fmaxf(mx, m);
        mn = fminf(mn, m);
      }
    }
  }

  while (cur < n1){
    FINALIZE(nextoff - curstart)
    curstart = nextoff;
    ++cur;
    if (cur < n1) nextoff = offs[cur + 1];
    s = 0.f; ss = 0.f;
    mx = -__builtin_huge_valf(); mn = __builtin_huge_valf();
  }
#undef FINALIZE
#undef PUTX2
}

// ---------- U GEMM: LDS-free MFMA, v2 slab-major A-loads (coalesced) ----------
__global__ __launch_bounds__(256) void k_u(const ushort* __restrict__ X2, const ushort* __restrict__ Wpk2,
                                           const float* __restrict__ sc, const float* __restrict__ Ub,
                                           float* __restrict__ uout, float* __restrict__ part,
                                           int Nn, int NBLK){
  __shared__ float su[64][68];
  __shared__ float pbn[2][4][64];
  int tid = threadIdx.x;
  int t   = blockIdx.y;
  int nbase = blockIdx.x*64;
  int lane = tid & 63, wv = tid >> 6;
  int li = lane & 15, kc = lane >> 4;
  int cbase = wv*48;

  f32x4 acc[4][3];
#pragma unroll
  for (int ri = 0; ri < 4; ++ri)
#pragma unroll
    for (int ci = 0; ci < 3; ++ci) acc[ri][ci] = (f32x4)0.f;

  const ushort* wb = Wpk2 + (size_t)t*192*320;

#pragma unroll 2
  for (int kt = 0; kt < 10; ++kt){
    const ushort* slab = X2 + (size_t)(t*10 + kt)*Nn*64;
    bf16x8 ah[4], al[4], bh[3];
#pragma unroll
    for (int ri = 0; ri < 4; ++ri){
      int row = nbase + ri*16 + li;
      if (row >= Nn) row = Nn - 1;
      const ushort* ap = slab + (size_t)row*64 + kc*16;
      ah[ri] = *(const bf16x8*)(ap);
      al[ri] = *(const bf16x8*)(ap + 8);
    }
#pragma unroll
    for (int ci = 0; ci < 3; ++ci){
      int col = cbase + ci*16 + li;
      bh[ci] = *(const bf16x8*)(wb + (size_t)col*320 + kt*32 + kc*8);
    }
#pragma unroll
    for (int ci = 0; ci < 3; ++ci)
#pragma unroll
      for (int ri = 0; ri < 4; ++ri){
        acc[ri][ci] = __builtin_amdgcn_mfma_f32_16x16x32_bf16(ah[ri], bh[ci], acc[ri][ci], 0, 0, 0);
        acc[ri][ci] = __builtin_amdgcn_mfma_f32_16x16x32_bf16(al[ri], bh[ci], acc[ri][ci], 0, 0, 0);
      }
  }

#define Y1_STORE(CI, OB) { _Pragma("unroll") for (int ri = 0; ri < 4; ++ri)               \
    { _Pragma("unroll") for (int r = 0; r < 4; ++r)                                        \
      su[ri*16 + kc*4 + r][(OB) + li] = acc[ri][CI][r]; } }
#define Y_ADD(CI, OB, SCOFF) { _Pragma("unroll") for (int ri = 0; ri < 4; ++ri)           \
    { _Pragma("unroll") for (int r = 0; r < 4; ++r){                                       \
      int node = ri*16 + kc*4 + r;                                                        \
      int gn = nbase + node; int gnc = (gn < Nn) ? gn : (Nn - 1);                          \
      float scl = sc[(size_t)gnc*2 + (SCOFF)];                                            \
      su[node][(OB) + li] += scl * acc[ri][CI][r]; } } }

  if (wv == 0){ Y1_STORE(0, 0)  Y1_STORE(1, 16) Y1_STORE(2, 32) }
  else if (wv == 1){ Y1_STORE(0, 48) }
  __syncthreads();
  if (wv == 1){ Y_ADD(1, 0, 0)  Y_ADD(2, 16, 0) }
  else if (wv == 2){ Y_ADD(0, 32, 0) Y_ADD(1, 48, 0) }
  __syncthreads();
  if (wv == 2){ Y_ADD(2, 0, 1) }
  else if (wv == 3){ Y_ADD(0, 16, 1) Y_ADD(1, 32, 1) Y_ADD(2, 48, 1) }
  __syncthreads();
#undef Y1_STORE
#undef Y_ADD

  for (int idx = tid; idx < 64*16; idx += 256){
    int n = idx >> 4, o4 = (idx & 15)*4;
    int gn = nbase + n;
    if (gn < Nn){
      float4 v = *(float4*)(&su[n][o4]);
      const float* ubp = Ub + t*64 + o4;
      v.x += ubp[0]; v.y += ubp[1]; v.z += ubp[2]; v.w += ubp[3];
      *(float4*)(&uout[(size_t)gn*256 + t*64 + o4]) = v;
    }
  }

  {
    int cl = tid & 63, grp = tid >> 6;
    float ubv = Ub[t*64 + cl];
    float ps = 0.f, pss = 0.f;
#pragma unroll
    for (int q = 0; q < 16; ++q){
      int nn = grp*16 + q;
      if (nbase + nn < Nn){
        float v = su[nn][cl] + ubv;
        ps += v;
        pss = fmaf(v, v, pss);
      }
    }
    pbn[0][grp][cl] = ps;
    pbn[1][grp][cl] = pss;
  }
  __syncthreads();
  if (tid < 128){
    int which = tid >> 6, cl = tid & 63;
    float v = pbn[which][0][cl] + pbn[which][1][cl] + pbn[which][2][cl] + pbn[which][3][cl];
    part[((size_t)t*NBLK + blockIdx.x)*128 + which*64 + cl] = v;
  }
}

// ---------- BN reduce stage 1 ----------
__global__ __launch_bounds__(256) void k_bnred(const float* __restrict__ part, float* __restrict__ part2,
                                               int NBLK){
  int g = blockIdx.x;
  int tid = threadIdx.x;
  int chunk = (NBLK + NBF - 1) / NBF;
  int b0 = g * chunk;
  int b1 = b0 + chunk; if (b1 > NBLK) b1 = NBLK;
#pragma unroll
  for (int half = 0; half < 2; ++half){
    int o = half*256 + tid;
    int t = o >> 7, idx = o & 127;
    float s = 0.f;
    for (int b = b0; b < b1; ++b)
      s += part[((size_t)t*NBLK + b)*128 + idx];
    part2[(size_t)g*512 + o] = s;
  }
}

// ---------- BN finalize ----------
__global__ __launch_bounds__(256) void k_bnfin(const float* __restrict__ part2, const float* __restrict__ gam,
                                               const float* __restrict__ bet, float* __restrict__ bnsc, int N){
  int c = threadIdx.x;
  int t = c >> 6, cl = c & 63;
  float s0 = 0.f, s1 = 0.f, t0 = 0.f, t1 = 0.f;
#pragma unroll 4
  for (int b = 0; b < NBF; b += 2){
    s0 += part2[(size_t)b*512 + t*128 + cl];
    t0 += part2[(size_t)b*512 + t*128 + 64 + cl];
    s1 += part2[(size_t)(b+1)*512 + t*128 + cl];
    t1 += part2[(size_t)(b+1)*512 + t*128 + 64 + cl];
  }
  float s = s0 + s1, ss = t0 + t1;
  float invN = 1.f / (float)N;
  float mu  = s * invN;
  float ex2 = ss * invN;
  float var = fmaxf(ex2 - mu*mu, 0.f);
  float inv = 1.f / sqrtf(var + 1e-5f);
  float scale = gam[c] * inv;
  bnsc[c]       = scale;
  bnsc[256 + c] = bet[c] - mu*scale;
}

// ---------- mix GEMM: reads u directly (BN folded in-reg), fused epilogue ----------
__global__ __launch_bounds__(256) void k_mix(const float* __restrict__ u, const ushort* __restrict__ Wm2,
                                             const float* __restrict__ bnsc,
                                             const float* __restrict__ mixb, const float* __restrict__ nf,
                                             float* __restrict__ outp, int Nn){
  int tid = threadIdx.x;
  int nbase = blockIdx.x*64;
  int lane = tid & 63, wv = tid >> 6;
  int li = lane & 15, kc = lane >> 4;

  f32x4 acc[4][4];
#pragma unroll
  for (int ri = 0; ri < 4; ++ri)
#pragma unroll
    for (int ci = 0; ci < 4; ++ci) acc[ri][ci] = (f32x4)0.f;

#pragma unroll 2
  for (int kt = 0; kt < 8; ++kt){
    int k0 = kt*32 + kc*8;
    float4 s40 = *(const float4*)(bnsc + k0);
    float4 s41 = *(const float4*)(bnsc + k0 + 4);
    float4 h40 = *(const float4*)(bnsc + 256 + k0);
    float4 h41 = *(const float4*)(bnsc + 256 + k0 + 4);
    bf16x8 ah[4], al[4], bh[4];
#pragma unroll
    for (int ri = 0; ri < 4; ++ri){
      int row = nbase + ri*16 + li;
      if (row >= Nn) row = Nn - 1;
      const float* up = u + (size_t)row*256 + k0;
      float4 v0 = *(const float4*)(up);
      float4 v1 = *(const float4*)(up + 4);
      float x[8];
      x[0] = fmaf(v0.x, s40.x, h40.x); x[1] = fmaf(v0.y, s40.y, h40.y);
      x[2] = fmaf(v0.z, s40.z, h40.z); x[3] = fmaf(v0.w, s40.w, h40.w);
      x[4] = fmaf(v1.x, s41.x, h41.x); x[5] = fmaf(v1.y, s41.y, h41.y);
      x[6] = fmaf(v1.z, s41.z, h41.z); x[7] = fmaf(v1.w, s41.w, h41.w);
      union { bf16x8 v; ushort u[8]; } hh, ll;
#pragma unroll
      for (int q = 0; q < 8; ++q){
        ushort hb = bf16h(x[q]);
        hh.u[q] = hb;
        ll.u[q] = bf16h(x[q] - bf16f(hb));
      }
      ah[ri] = hh.v;
      al[ri] = ll.v;
    }
#pragma unroll
    for (int ci = 0; ci < 4; ++ci){
      int col = wv*64 + ci*16 + li;
      bh[ci] = *(const bf16x8*)(Wm2 + (size_t)col*256 + kt*32 + kc*8);
    }
#pragma unroll
    for (int ci = 0; ci < 4; ++ci)
#pragma unroll
      for (int ri = 0; ri < 4; ++ri){
        acc[ri][ci] = __builtin_amdgcn_mfma_f32_16x16x32_bf16(ah[ri], bh[ci], acc[ri][ci], 0, 0, 0);
        acc[ri][ci] = __builtin_amdgcn_mfma_f32_16x16x32_bf16(al[ri], bh[ci], acc[ri][ci], 0, 0, 0);
      }
  }

  __syncthreads();
#pragma unroll
  for (int ri = 0; ri < 4; ++ri){
#pragma unroll
    for (int r = 0; r < 4; ++r){
      int node = ri*16 + kc*4 + r;
      int gn = nbase + node;
      if (gn < Nn){
#pragma unroll
        for (int ci = 0; ci < 4; ++ci){
          int col = wv*64 + ci*16 + li;
          float m = acc[ri][ci][r] + mixb[col];
          m = (m > 0.f) ? m : 0.01f*m;
          float o = m + nf[(size_t)gn*256 + col];
          outp[(size_t)gn*256 + col] = fmaxf(o, 0.f);
        }
      }
    }
  }
}

// ---------- host launcher ----------
extern "C" void kernel_launch(void* const* d_in, const int* in_sizes, int n_in,
                              void* d_out, int out_size, void* d_ws, size_t ws_size,
                              hipStream_t stream){
  const float* nf   = (const float*)d_in[0];
  const float* ef   = (const float*)d_in[1];
  const int*   srcv = (const int*)  d_in[2];
  const int*   dstv = (const int*)  d_in[3];
  const float* Mw   = (const float*)d_in[4];
  const float* Mb   = (const float*)d_in[5];
  const float* Uw   = (const float*)d_in[6];
  const float* Ub   = (const float*)d_in[7];
  const float* gam  = (const float*)d_in[8];
  const float* bet  = (const float*)d_in[9];
  const float* mixw = (const float*)d_in[10];
  const float* mixb = (const float*)d_in[11];
  int N = in_sizes[0] / 256;
  int E = in_sizes[2];
  float* out = (float*)d_out;
  int NBLK = (N + 63)/64;

  char* wp = (char*)d_ws;
  auto alloc = [&](size_t bytes){
    char* p = wp;
    wp += (bytes + 1023) & ~(size_t)1023;
    return (void*)p;
  };
  int*      cnt   = (int*)     alloc((size_t)N*4);
  int*      offs  = (int*)     alloc((size_t)(N+1)*4);
  int*      cur   = (int*)     alloc((size_t)N*4);
  int*      bsum  = (int*)     alloc(256*4);
  int*      esrc  = (int*)     alloc((size_t)E*4);
  _Float16* efh   = (_Float16*)alloc((size_t)E*32*2);
  _Float16* nfh   = (_Float16*)alloc((size_t)N*256*2);
  float*    B     = (float*)   alloc((size_t)N*256*4);
  float*    sc    = (float*)   alloc((size_t)N*2*4);
  float*    part  = (float*)   alloc((size_t)4*NBLK*128*4);
  float*    part2 = (float*)   alloc((size_t)NBF*512*4);
  float*    bnsc  = (float*)   alloc(512*4);
  ushort*   X2    = (ushort*)  alloc((size_t)N*2560*2);
  ushort*   Wpk2  = (ushort*)  alloc((size_t)4*192*320*2);
  ushort*   Wm2   = (ushort*)  alloc((size_t)256*256*2);
  _Float16* Wall  = (_Float16*)alloc((size_t)4*4*3*64*8*2);

  hipMemsetAsync(cnt,  0, (size_t)N*4,  stream);
  hipMemsetAsync(cur,  0, (size_t)N*4,  stream);

  k_tU  <<<(4*192*320 + 255)/256, 256, 0, stream>>>(Uw, Wpk2);
  k_tMm <<<(256*256 + 255)/256, 256, 0, stream>>>(mixw, Wm2);
  k_tW  <<<(4*4*3*64*8 + 255)/256, 256, 0, stream>>>(Mw, Wall);
  k_hist<<<(E + 255)/256, 256, 0, stream>>>(dstv, cnt, E);
  k_ab  <<<2048, 256, 0, stream>>>(nf, Mw, Mb, nfh, B, X2, N);

  int NB = (N + 255)/256;
  k_scan1<<<NB, 256, 0, stream>>>(cnt, offs, bsum, N);
  k_scan2<<<1, 256, 0, stream>>>(bsum, NB);
  k_scan3<<<NB, 256, 0, stream>>>(offs, bsum, N, E);
  k_fillp<<<(E + 255)/256, 256, 0, stream>>>(dstv, srcv, ef, offs, cur, esrc, efh, E);

  k_agg<<<(N + NPB - 1)/NPB, 256, 0, stream>>>(offs, esrc, efh, nfh, B, Wall, X2, sc, N, E);

  dim3 ugrid(NBLK, 4);
  k_u<<<ugrid, 256, 0, stream>>>(X2, Wpk2, sc, Ub, out, part, N, NBLK);

  k_bnred<<<NBF, 256, 0, stream>>>(part, part2, NBLK);
  k_bnfin<<<1, 256, 0, stream>>>(part2, gam, bet, bnsc, N);
  k_mix  <<<NBLK, 256, 0, stream>>>(out, Wm2, bnsc, mixb, nf, out, N);
}